// Round 5
// baseline (423.692 us; speedup 1.0000x reference)
//
#include <hip/hip_runtime.h>

#define D_MODEL 2048
#define SEQ 2048
#define BATCH 2
#define NH 16
#define HD 128
#define MTOT 4096   // BATCH*SEQ
#define NQKV 6144   // 3*D_MODEL
#define QSTRIDE 4096  // QK buffer row stride (Q cols 0..2047, K cols 2048..4095)

// 1/sqrt(128) * log2(e)
static constexpr float SCALE_LOG2E = 0.08838834764831845f * 1.4426950408889634f;

typedef __bf16 bf16x8 __attribute__((ext_vector_type(8)));
typedef _Float16 f16x4 __attribute__((ext_vector_type(4)));
typedef float f32x4 __attribute__((ext_vector_type(4)));

__device__ inline unsigned short f2bf(float f) {
  unsigned int u = __builtin_bit_cast(unsigned int, f);
  u += 0x7fffu + ((u >> 16) & 1u);
  return (unsigned short)(u >> 16);
}

__device__ inline float bf2f(unsigned int u) {
  return __builtin_bit_cast(float, u << 16);
}

__device__ inline float fast_exp2(float x) {
#if __has_builtin(__builtin_amdgcn_exp2f)
  return __builtin_amdgcn_exp2f(x);
#else
  return exp2f(x);
#endif
}

__device__ inline unsigned int bperm(int srcLane, unsigned int v) {
  return (unsigned int)__builtin_amdgcn_ds_bpermute(srcLane << 2, (int)v);
}

__device__ inline void gload_lds16(const void* g, void* s) {
  __builtin_amdgcn_global_load_lds(
      (__attribute__((address_space(1))) void*)g,
      (__attribute__((address_space(3))) void*)s, 16, 0, 0);
}

#define BARX() __builtin_amdgcn_s_barrier()
#define PRIO(x) __builtin_amdgcn_s_setprio(x)
#define LGK0()                                              \
  do {                                                      \
    asm volatile("s_waitcnt lgkmcnt(0)" ::: "memory");      \
    __builtin_amdgcn_sched_barrier(0);                      \
  } while (0)
#define VMW(n) asm volatile("s_waitcnt vmcnt(" #n ")" ::: "memory")

// ---------------- fused fp32 -> bf16 conversion (all 5 inputs) -------------
__global__ __launch_bounds__(256) void cvt_all(
    const float* __restrict__ x, const float* __restrict__ wq,
    const float* __restrict__ wk, const float* __restrict__ wv,
    const float* __restrict__ wo, unsigned short* __restrict__ xb,
    unsigned short* __restrict__ wqkv, unsigned short* __restrict__ wob) {
  const int y = blockIdx.y;
  const float* src;
  unsigned short* dst;
  int n4;
  if (y == 0) { src = x; dst = xb; n4 = MTOT * D_MODEL / 4; }
  else if (y == 4) { src = wo; dst = wob; n4 = D_MODEL * D_MODEL / 4; }
  else {
    src = (y == 1) ? wq : (y == 2) ? wk : wv;
    dst = wqkv + (size_t)(y - 1) * D_MODEL * D_MODEL;
    n4 = D_MODEL * D_MODEL / 4;
  }
  int i = blockIdx.x * 256 + threadIdx.x;
  if (i < n4) {
    float4 v = ((const float4*)src)[i];
    ushort4 o;
    o.x = f2bf(v.x); o.y = f2bf(v.y); o.z = f2bf(v.z); o.w = f2bf(v.w);
    ((ushort4*)dst)[i] = o;
  }
}

// ============================================================================
// gemm_qk: C[4096,4096] = A[4096,2048] * B[4096,2048]^T -> bf16 QK buffer.
// BM=BN=256, BK=64, 8 waves (2M x 4N -> 128x64/wave), double-buffered LDS,
// 4 phases per K-tile (16 MFMA each), counted vmcnt.  256 blocks = 1 round.
// ============================================================================
__global__ __launch_bounds__(512, 2) void gemm_qk(
    const unsigned short* __restrict__ A, const unsigned short* __restrict__ B,
    unsigned short* __restrict__ QK) {
  extern __shared__ __align__(16) char smem[];
  const int tid = threadIdx.x;
  const int lane = tid & 63;
  const int wave = tid >> 6;
  const int quad = lane >> 4;
  const int l15 = lane & 15;
  const int bid = blockIdx.x;
  const int wgid = (bid & 7) * 32 + (bid >> 3);  // bijective XCD swizzle
  const int tm = wgid >> 4, tn = wgid & 15;
  const int m0 = tm * 256, n0 = tn * 256;
  const int wm = wave >> 2;  // 0..1
  const int wn = wave & 3;   // 0..3

  const unsigned short* Ag = A + (size_t)(m0 + wave * 8 + (lane >> 3)) * 2048 +
                             (((lane & 7) ^ (lane >> 3)) * 8);
  const unsigned short* Bg = B + (size_t)(n0 + wave * 8 + (lane >> 3)) * 2048 +
                             (((lane & 7) ^ (lane >> 3)) * 8);
  char* sd = smem + wave * 1024;

  const int arow0 = (wm * 128 + l15) * 128;  // byte base, A frag (mh=0,mi=0)
  const int brow0 = (wn * 64 + l15) * 128;
  const int sk0 = (quad ^ (l15 & 7)) * 16;
  const int sk1 = ((4 + quad) ^ (l15 & 7)) * 16;

  f32x4 acc[8][4] = {};
  bf16x8 a[4][2], bl[2][2], bh[2][2];

#define QSA(u, nb, ko) \
  gload_lds16(Ag + (size_t)(u) * 64 * 2048 + (ko), sd + (nb) * 65536 + (u) * 8192)
#define QSB(u, nb, ko) \
  gload_lds16(Bg + (size_t)(u) * 64 * 2048 + (ko), sd + (nb) * 65536 + 32768 + (u) * 8192)
#define QRA(mh, cb)                                                               \
  _Pragma("unroll") for (int mi = 0; mi < 4; mi++) {                              \
    a[mi][0] = *(const bf16x8*)(smem + (cb) * 65536 + arow0 + ((mh) * 64 + mi * 16) * 128 + sk0); \
    a[mi][1] = *(const bf16x8*)(smem + (cb) * 65536 + arow0 + ((mh) * 64 + mi * 16) * 128 + sk1); \
  }
#define QRB(dst, nh, cb)                                                          \
  _Pragma("unroll") for (int ni = 0; ni < 2; ni++) {                              \
    dst[ni][0] = *(const bf16x8*)(smem + (cb) * 65536 + 32768 + brow0 + ((nh) * 32 + ni * 16) * 128 + sk0); \
    dst[ni][1] = *(const bf16x8*)(smem + (cb) * 65536 + 32768 + brow0 + ((nh) * 32 + ni * 16) * 128 + sk1); \
  }
#define QMM(mh, bsrc, nh)                                                         \
  _Pragma("unroll") for (int mi = 0; mi < 4; mi++)                                \
  _Pragma("unroll") for (int ni = 0; ni < 2; ni++) {                              \
    acc[(mh) * 4 + mi][(nh) * 2 + ni] = __builtin_amdgcn_mfma_f32_16x16x32_bf16(  \
        a[mi][0], bsrc[ni][0], acc[(mh) * 4 + mi][(nh) * 2 + ni], 0, 0, 0);       \
    acc[(mh) * 4 + mi][(nh) * 2 + ni] = __builtin_amdgcn_mfma_f32_16x16x32_bf16(  \
        a[mi][1], bsrc[ni][1], acc[(mh) * 4 + mi][(nh) * 2 + ni], 0, 0, 0);       \
  }

  // prologue: tile 0 fully staged
  QSB(0, 0, 0); QSB(1, 0, 0); QSB(2, 0, 0); QSB(3, 0, 0);
  QSA(0, 0, 0); QSA(2, 0, 0); QSA(1, 0, 0); QSA(3, 0, 0);
  VMW(0);
  BARX();

#define QKTILE(t, cb, nb)                                                         \
  {                                                                               \
    const int ko = (((t) + 1) & 31) * 64;                                         \
    /* ph0 */                                                                     \
    QRA(0, cb); QRB(bl, 0, cb);                                                   \
    QSB(0, nb, ko); QSB(1, nb, ko);                                               \
    BARX(); LGK0(); PRIO(1); QMM(0, bl, 0); PRIO(0); BARX();                      \
    /* ph1 */                                                                     \
    QRB(bh, 1, cb);                                                               \
    QSB(2, nb, ko); QSB(3, nb, ko);                                               \
    BARX(); LGK0(); PRIO(1); QMM(0, bh, 1); PRIO(0); VMW(4); BARX();              \
    /* ph2 */                                                                     \
    QRA(1, cb);                                                                   \
    QSA(0, nb, ko); QSA(2, nb, ko);                                               \
    BARX(); LGK0(); PRIO(1); QMM(1, bl, 0); PRIO(0); BARX();                      \
    /* ph3 */                                                                     \
    QSA(1, nb, ko); QSA(3, nb, ko);                                               \
    PRIO(1); QMM(1, bh, 1); PRIO(0); VMW(2); BARX();                              \
  }

  for (int t = 0; t < 32; t += 2) {
    QKTILE(t, 0, 1);
    QKTILE(t + 1, 1, 0);
  }

  // epilogue: bf16 stores, row stride 4096
#pragma unroll
  for (int mi = 0; mi < 8; mi++)
#pragma unroll
    for (int ni = 0; ni < 4; ni++) {
      const int mm = m0 + wm * 128 + mi * 16 + quad * 4;
      const int nn = n0 + wn * 64 + ni * 16 + l15;
#pragma unroll
      for (int r = 0; r < 4; r++)
        QK[(size_t)(mm + r) * QSTRIDE + nn] = f2bf(acc[mi][ni][r]);
    }
#undef QSA
#undef QSB
#undef QRA
#undef QRB
#undef QMM
#undef QKTILE
}

// ============================================================================
// Shared 128x256 core for gemm_v / gemm_out: BM=128, BN=256, BK=64,
// 8 waves (4M x 2N -> 32x128/wave), TRIPLE-buffered LDS, 2 phases/K-tile,
// stage tile t+2 during t, single vmcnt(6)/tile.  256 blocks = 1 round.
// ============================================================================
#define VCORE_BODY(Aptr, Bptr)                                                    \
  const int tid = threadIdx.x;                                                    \
  const int lane = tid & 63;                                                      \
  const int wave = tid >> 6;                                                      \
  const int quad = lane >> 4;                                                     \
  const int l15 = lane & 15;                                                      \
  const int bid = blockIdx.x;                                                     \
  const int wgid = (bid & 7) * 32 + (bid >> 3);                                   \
  const int tm = wgid >> 3, tn = wgid & 7;                                        \
  const int m0 = tm * 128, n0 = tn * 256;                                         \
  const int wm = wave >> 1; /* 0..3 */                                            \
  const int wn = wave & 1;  /* 0..1 */                                            \
  const unsigned short* Ag = (Aptr) + (size_t)(m0 + wave * 8 + (lane >> 3)) * 2048 + \
                             (((lane & 7) ^ (lane >> 3)) * 8);                    \
  const unsigned short* Bg = (Bptr) + (size_t)(n0 + wave * 8 + (lane >> 3)) * 2048 + \
                             (((lane & 7) ^ (lane >> 3)) * 8);                    \
  char* sd = smem + wave * 1024;                                                  \
  const int arow0 = (wm * 32 + l15) * 128;                                        \
  const int brow0 = (wn * 128 + l15) * 128;                                       \
  const int sk0 = (quad ^ (l15 & 7)) * 16;                                        \
  const int sk1 = ((4 + quad) ^ (l15 & 7)) * 16;                                  \
  f32x4 acc[2][8] = {};                                                           \
  bf16x8 a[2][2], bl[4][2], bh[4][2];

#define VSA(u, nb, ko) \
  gload_lds16(Ag + (size_t)(u) * 64 * 2048 + (ko), sd + (nb) * 49152 + (u) * 8192)
#define VSB(u, nb, ko) \
  gload_lds16(Bg + (size_t)(u) * 64 * 2048 + (ko), sd + (nb) * 49152 + 16384 + (u) * 8192)
#define VRA(cb)                                                                   \
  _Pragma("unroll") for (int mi = 0; mi < 2; mi++) {                              \
    a[mi][0] = *(const bf16x8*)(smem + (cb) * 49152 + arow0 + mi * 2048 + sk0);   \
    a[mi][1] = *(const bf16x8*)(smem + (cb) * 49152 + arow0 + mi * 2048 + sk1);   \
  }
#define VRB(dst, nh, cb)                                                          \
  _Pragma("unroll") for (int ni = 0; ni < 4; ni++) {                              \
    dst[ni][0] = *(const bf16x8*)(smem + (cb) * 49152 + 16384 + brow0 + ((nh) * 64 + ni * 16) * 128 + sk0); \
    dst[ni][1] = *(const bf16x8*)(smem + (cb) * 49152 + 16384 + brow0 + ((nh) * 64 + ni * 16) * 128 + sk1); \
  }
#define VMM(bsrc, nh)                                                             \
  _Pragma("unroll") for (int mi = 0; mi < 2; mi++)                                \
  _Pragma("unroll") for (int ni = 0; ni < 4; ni++) {                              \
    acc[mi][(nh) * 4 + ni] = __builtin_amdgcn_mfma_f32_16x16x32_bf16(             \
        a[mi][0], bsrc[ni][0], acc[mi][(nh) * 4 + ni], 0, 0, 0);                  \
    acc[mi][(nh) * 4 + ni] = __builtin_amdgcn_mfma_f32_16x16x32_bf16(             \
        a[mi][1], bsrc[ni][1], acc[mi][(nh) * 4 + ni], 0, 0, 0);                  \
  }
#define VSTAGE6(nb, ko)                                                           \
  VSA(0, nb, ko); VSA(1, nb, ko); VSB(0, nb, ko);                                 \
  VSB(1, nb, ko); VSB(2, nb, ko); VSB(3, nb, ko);

#define VTILE(t, cb, nb)                                                          \
  {                                                                               \
    const int ko = (((t) + 2) & 31) * 64;                                         \
    /* ph0 */                                                                     \
    VRA(cb); VRB(bl, 0, cb);                                                      \
    VSA(0, nb, ko); VSA(1, nb, ko); VSB(0, nb, ko);                               \
    BARX(); LGK0(); PRIO(1); VMM(bl, 0); PRIO(0); BARX();                         \
    /* ph1 */                                                                     \
    VRB(bh, 1, cb);                                                               \
    VSB(1, nb, ko); VSB(2, nb, ko); VSB(3, nb, ko);                               \
    BARX(); LGK0(); PRIO(1); VMM(bh, 1); PRIO(0); VMW(6); BARX();                 \
  }

#define VCORE_LOOP()                                                              \
  VSTAGE6(0, 0);                                                                  \
  VSTAGE6(1, 64);                                                                 \
  VMW(6);                                                                         \
  BARX();                                                                         \
  for (int t = 0; t < 30; t += 3) {                                               \
    VTILE(t + 0, 0, 2);                                                           \
    VTILE(t + 1, 1, 0);                                                           \
    VTILE(t + 2, 2, 1);                                                           \
  }                                                                               \
  VTILE(30, 0, 2);                                                                \
  VTILE(31, 1, 0);

// ---------------- V-projection GEMM -> transposed bf16 Vt[bh][d][s] --------
__global__ __launch_bounds__(512, 2) void gemm_v(
    const unsigned short* __restrict__ A, const unsigned short* __restrict__ B,
    unsigned short* __restrict__ Vt) {
  extern __shared__ __align__(16) char smem[];
  VCORE_BODY(A, B);
  VCORE_LOOP();

  // transpose via LDS: T[2 heads][128 d][136 s-pad] bf16
  VMW(0);
  BARX();
  unsigned short* T = (unsigned short*)smem;
  const int h0 = n0 >> 7;  // = tn*2
  const int bb = m0 >> 11;
  const int sbase = m0 & (SEQ - 1);
#pragma unroll
  for (int mi = 0; mi < 2; mi++)
#pragma unroll
    for (int q = 0; q < 8; q++) {
      const int d = q * 16 + l15;
      const int slocal = wm * 32 + mi * 16 + quad * 4;
      ushort4 hv;
      hv.x = f2bf(acc[mi][q][0]);
      hv.y = f2bf(acc[mi][q][1]);
      hv.z = f2bf(acc[mi][q][2]);
      hv.w = f2bf(acc[mi][q][3]);
      *(ushort4*)(T + wn * 17408 + d * 136 + slocal) = hv;
    }
  BARX();
  const int hd2 = tid >> 8;          // 0..1
  const int d = (tid >> 1) & 127;
  const int sc = (tid & 1) * 64;
  const size_t vrow = ((size_t)((bb * NH + h0 + hd2) * HD + d)) * SEQ + sbase + sc;
#pragma unroll
  for (int j = 0; j < 8; j++) {
    float4 c4 = *(const float4*)(T + hd2 * 17408 + d * 136 + sc + j * 8);
    *(float4*)(Vt + vrow + j * 8) = c4;
  }
}

// ---------------- output-projection GEMM -> f32 C ---------------------------
__global__ __launch_bounds__(512, 2) void gemm_out(
    const unsigned short* __restrict__ A, const unsigned short* __restrict__ B,
    float* __restrict__ C) {
  extern __shared__ __align__(16) char smem[];
  VCORE_BODY(A, B);
  VCORE_LOOP();

#pragma unroll
  for (int mi = 0; mi < 2; mi++)
#pragma unroll
    for (int q = 0; q < 8; q++) {
      const int mm = m0 + wm * 32 + mi * 16 + quad * 4;
      const int nn = n0 + wn * 128 + q * 16 + l15;
#pragma unroll
      for (int r = 0; r < 4; r++)
        C[(size_t)(mm + r) * D_MODEL + nn] = acc[mi][q][r];
    }
}

// ---------------- flash attention v5 --------------------------------------
// PV on mfma_f32_16x16x32_bf16 (A/B operand-map symmetry verified every run
// by the passing bf16 GEMMs; the f16 K=32 variant of v4 was the unverified
// element and failed).  P packed to bf16 words; repack via unconditional
// ds_bpermute pulls + value select (no ternary-of-shfl hazard).  lsum is
// accumulated from the ROUNDED bf16 p so numerator/denominator stay
// consistent.  V read directly from L2-resident Vt (bf16).
__global__ __launch_bounds__(256, 2) void flash_attn(
    const unsigned short* __restrict__ QK, const unsigned short* __restrict__ Vt,
    unsigned short* __restrict__ Og) {
  __shared__ __align__(16) unsigned short Ks[2][64 * 128];
  const int tid = threadIdx.x;
  const int lane = tid & 63;
  const int wave = tid >> 6;
  const int quad = lane >> 4;
  const int l15 = lane & 15;
  const int id = blockIdx.x;
  const int xr = id & 7;
  const int kk = id >> 3;
  const int bh = xr * 4 + (kk >> 4);
  const int b = bh >> 4, h = bh & 15;
  const int q0 = (kk & 15) * 128;

  const size_t kbase = (size_t)(b * SEQ) * QSTRIDE + D_MODEL + h * HD;
  const size_t vbase = (size_t)bh * HD * SEQ;

  bf16x8 qf[2][4];
#pragma unroll
  for (int t = 0; t < 2; t++)
#pragma unroll
    for (int kc = 0; kc < 4; kc++)
      qf[t][kc] = *(const bf16x8*)(QK + (size_t)(b * SEQ + q0 + wave * 32 + t * 16 + l15) * QSTRIDE +
                                   h * HD + kc * 32 + quad * 8);

  // K staging (swizzled source, linear LDS dest)
  const unsigned short* kg[4];
  int klofs[4];
#pragma unroll
  for (int i = 0; i < 4; i++) {
    int krow = wave * 16 + i * 4 + quad;
    int kc_ = l15 ^ (i * 4 + quad);
    kg[i] = QK + kbase + (size_t)krow * QSTRIDE + kc_ * 8;
    klofs[i] = (wave * 16 + i * 4) * 128;
  }

  // V fragment pointers: row d = jt*16+l15, chunk quad*8 (keys advance /iter)
  const unsigned short* vp[8];
#pragma unroll
  for (int jt = 0; jt < 8; jt++)
    vp[jt] = Vt + vbase + (size_t)(jt * 16 + l15) * SEQ + quad * 8;

#pragma unroll
  for (int i = 0; i < 4; i++) gload_lds16(kg[i], &Ks[0][klofs[i]]);
#pragma unroll
  for (int i = 0; i < 4; i++) kg[i] += 64 * QSTRIDE;
  VMW(0);
  __syncthreads();

  float lsum[2] = {0.f, 0.f};
  f32x4 Oa[2][8] = {};

  const int laA = l15 + 32 * (quad & 1);  // source lane for B-frag words 0,1
  const int laB = laA + 16;               // words 2,3
  const bool hi = quad >= 2;              // register select: js = 2g + (quad>>1)

  for (int it = 0; it < SEQ / 64; ++it) {
    const int cur = it & 1;
    if (it < SEQ / 64 - 1) {
#pragma unroll
      for (int i = 0; i < 4; i++) gload_lds16(kg[i], &Ks[cur ^ 1][klofs[i]]);
#pragma unroll
      for (int i = 0; i < 4; i++) kg[i] += 64 * QSTRIDE;
    }

    // ---- QK^T: 32 MFMA bf16 K=32 ----
    const unsigned short* kb = &Ks[cur][0];
    f32x4 sacc[2][4] = {};
    PRIO(1);
#pragma unroll
    for (int js = 0; js < 4; js++)
#pragma unroll
      for (int kc = 0; kc < 4; kc++) {
        bf16x8 kf = *(const bf16x8*)(kb + (js * 16 + l15) * 128 + (((kc * 4 + quad) ^ l15) * 8));
        sacc[0][js] = __builtin_amdgcn_mfma_f32_16x16x32_bf16(kf, qf[0][kc], sacc[0][js], 0, 0, 0);
        sacc[1][js] = __builtin_amdgcn_mfma_f32_16x16x32_bf16(kf, qf[1][kc], sacc[1][js], 0, 0, 0);
      }
    PRIO(0);

    // ---- softmax -> packed bf16 words pw[t][js][w]; lsum from ROUNDED p ----
    unsigned int pw[2][4][2];
#pragma unroll
    for (int t = 0; t < 2; t++)
#pragma unroll
      for (int js = 0; js < 4; js++) {
        float p0 = fast_exp2(sacc[t][js][0] * SCALE_LOG2E);
        float p1 = fast_exp2(sacc[t][js][1] * SCALE_LOG2E);
        float p2 = fast_exp2(sacc[t][js][2] * SCALE_LOG2E);
        float p3 = fast_exp2(sacc[t][js][3] * SCALE_LOG2E);
        unsigned int b0 = f2bf(p0), b1 = f2bf(p1), b2 = f2bf(p2), b3 = f2bf(p3);
        pw[t][js][0] = b0 | (b1 << 16);
        pw[t][js][1] = b2 | (b3 << 16);
        lsum[t] += (bf2f(b0) + bf2f(b1)) + (bf2f(b2) + bf2f(b3));
      }

    // ---- repack to K=32 B-frags: pb8[t][g] elem j = P[key=g*32+quad*8+j][q=l15]
    // word w <- word (w&1) of pw[t][2g+(quad>>1)] from lane l15+16*((quad&1)*2+(w>>1))
    bf16x8 pb8[2][2];
#pragma unroll
    for (int t = 0; t < 2; t++)
#pragma unroll
      for (int g = 0; g < 2; g++) {
        const int j0 = 2 * g, j1 = 2 * g + 1;
        unsigned int a0 = bperm(laA, pw[t][j0][0]), c0 = bperm(laA, pw[t][j1][0]);
        unsigned int a1 = bperm(laA, pw[t][j0][1]), c1 = bperm(laA, pw[t][j1][1]);
        unsigned int a2 = bperm(laB, pw[t][j0][0]), c2 = bperm(laB, pw[t][j1][0]);
        unsigned int a3 = bperm(laB, pw[t][j0][1]), c3 = bperm(laB, pw[t][j1][1]);
        uint4 u;
        u.x = hi ? c0 : a0;
        u.y = hi ? c1 : a1;
        u.z = hi ? c2 : a2;
        u.w = hi ? c3 : a3;
        pb8[t][g] = __builtin_bit_cast(bf16x8, u);
      }

    // ---- PV: V frags from global (L2), bf16 K=32, full rate ----
    const int ko = it * 64;
    PRIO(1);
#pragma unroll
    for (int jt = 0; jt < 8; jt++) {
      bf16x8 v0 = *(const bf16x8*)(vp[jt] + ko);
      bf16x8 v1 = *(const bf16x8*)(vp[jt] + ko + 32);
      Oa[0][jt] = __builtin_amdgcn_mfma_f32_16x16x32_bf16(v0, pb8[0][0], Oa[0][jt], 0, 0, 0);
      Oa[1][jt] = __builtin_amdgcn_mfma_f32_16x16x32_bf16(v0, pb8[1][0], Oa[1][jt], 0, 0, 0);
      Oa[0][jt] = __builtin_amdgcn_mfma_f32_16x16x32_bf16(v1, pb8[0][1], Oa[0][jt], 0, 0, 0);
      Oa[1][jt] = __builtin_amdgcn_mfma_f32_16x16x32_bf16(v1, pb8[1][1], Oa[1][jt], 0, 0, 0);
    }
    PRIO(0);

    if (it < SEQ / 64 - 1) {
      VMW(0);  // own-wave K staging done
    }
    __syncthreads();
  }

  float inv[2];
#pragma unroll
  for (int t = 0; t < 2; t++) {
    float s = lsum[t];
    s += __shfl_xor(s, 16);
    s += __shfl_xor(s, 32);
    inv[t] = 1.0f / s;
  }

#pragma unroll
  for (int t = 0; t < 2; t++) {
    const size_t rowbase = (size_t)(b * SEQ + q0 + wave * 32 + t * 16 + l15) * D_MODEL + h * HD;
#pragma unroll
    for (int jt = 0; jt < 8; jt++) {
      ushort4 o;
      o.x = f2bf(Oa[t][jt][0] * inv[t]);
      o.y = f2bf(Oa[t][jt][1] * inv[t]);
      o.z = f2bf(Oa[t][jt][2] * inv[t]);
      o.w = f2bf(Oa[t][jt][3] * inv[t]);
      *(ushort4*)(Og + rowbase + jt * 16 + quad * 4) = o;
    }
  }
}

// ---------------- launcher ----------------
extern "C" void kernel_launch(void* const* d_in, const int* in_sizes, int n_in,
                              void* d_out, int out_size, void* d_ws, size_t ws_size,
                              hipStream_t stream) {
  const float* x = (const float*)d_in[0];
  const float* wq = (const float*)d_in[1];
  const float* wk = (const float*)d_in[2];
  const float* wv = (const float*)d_in[3];
  const float* wo = (const float*)d_in[4];
  float* out = (float*)d_out;
  char* ws = (char*)d_ws;
  const size_t MB = 1u << 20;
  if (ws_size < 96 * MB) return;

  unsigned short* xb = (unsigned short*)(ws);             // 16 MB (reused as Ab)
  unsigned short* wqkv = (unsigned short*)(ws + 16 * MB); // 24 MB [6144,2048]
  unsigned short* wob = (unsigned short*)(ws + 40 * MB);  // 8 MB
  unsigned short* QKb = (unsigned short*)(ws + 48 * MB);  // 32 MB [4096,4096]
  unsigned short* Vtb = (unsigned short*)(ws + 80 * MB);  // 16 MB bf16
  unsigned short* Ab = xb;

  static int lds_set = 0;
  if (!lds_set) {
    hipFuncSetAttribute((const void*)gemm_qk,
                        hipFuncAttributeMaxDynamicSharedMemorySize, 131072);
    hipFuncSetAttribute((const void*)gemm_v,
                        hipFuncAttributeMaxDynamicSharedMemorySize, 147456);
    hipFuncSetAttribute((const void*)gemm_out,
                        hipFuncAttributeMaxDynamicSharedMemorySize, 147456);
    lds_set = 1;
  }

  cvt_all<<<dim3(8192, 5), 256, 0, stream>>>(x, wq, wk, wv, wo, xb, wqkv, wob);

  gemm_qk<<<256, 512, 131072, stream>>>(xb, wqkv, QKb);
  gemm_v<<<256, 512, 147456, stream>>>(xb, wqkv + (size_t)4096 * 2048, Vtb);

  flash_attn<<<512, 256, 0, stream>>>(QKb, Vtb, Ab);

  gemm_out<<<256, 512, 147456, stream>>>(Ab, wob, out);
}

// Round 7
// 363.228 us; speedup vs baseline: 1.1665x; 1.1665x over previous
//
#include <hip/hip_runtime.h>

#define D_MODEL 2048
#define SEQ 2048
#define BATCH 2
#define NH 16
#define HD 128
#define MTOT 4096   // BATCH*SEQ
#define NQKV 6144   // 3*D_MODEL
#define QSTRIDE 4096  // QK buffer row stride (Q cols 0..2047, K cols 2048..4095)

// 1/sqrt(128) * log2(e)
static constexpr float SCALE_LOG2E = 0.08838834764831845f * 1.4426950408889634f;

typedef __bf16 bf16x8 __attribute__((ext_vector_type(8)));
typedef float f32x4 __attribute__((ext_vector_type(4)));

__device__ inline unsigned short f2bf(float f) {
  unsigned int u = __builtin_bit_cast(unsigned int, f);
  u += 0x7fffu + ((u >> 16) & 1u);
  return (unsigned short)(u >> 16);
}

__device__ inline float bf2f(unsigned int u) {
  return __builtin_bit_cast(float, u << 16);
}

__device__ inline float fast_exp2(float x) {
#if __has_builtin(__builtin_amdgcn_exp2f)
  return __builtin_amdgcn_exp2f(x);
#else
  return exp2f(x);
#endif
}

__device__ inline unsigned int bperm(int srcLane, unsigned int v) {
  return (unsigned int)__builtin_amdgcn_ds_bpermute(srcLane << 2, (int)v);
}

__device__ inline void gload_lds16(const void* g, void* s) {
  __builtin_amdgcn_global_load_lds(
      (__attribute__((address_space(1))) void*)g,
      (__attribute__((address_space(3))) void*)s, 16, 0, 0);
}

#define BARX() __builtin_amdgcn_s_barrier()
#define PRIO(x) __builtin_amdgcn_s_setprio(x)
#define LGK0()                                              \
  do {                                                      \
    asm volatile("s_waitcnt lgkmcnt(0)" ::: "memory");      \
    __builtin_amdgcn_sched_barrier(0);                      \
  } while (0)
#define VMW(n) asm volatile("s_waitcnt vmcnt(" #n ")" ::: "memory")

// ---------------- fused fp32 -> bf16 conversion (all 5 inputs) -------------
__global__ __launch_bounds__(256) void cvt_all(
    const float* __restrict__ x, const float* __restrict__ wq,
    const float* __restrict__ wk, const float* __restrict__ wv,
    const float* __restrict__ wo, unsigned short* __restrict__ xb,
    unsigned short* __restrict__ wqkv, unsigned short* __restrict__ wob) {
  const int y = blockIdx.y;
  const float* src;
  unsigned short* dst;
  int n4;
  if (y == 0) { src = x; dst = xb; n4 = MTOT * D_MODEL / 4; }
  else if (y == 4) { src = wo; dst = wob; n4 = D_MODEL * D_MODEL / 4; }
  else {
    src = (y == 1) ? wq : (y == 2) ? wk : wv;
    dst = wqkv + (size_t)(y - 1) * D_MODEL * D_MODEL;
    n4 = D_MODEL * D_MODEL / 4;
  }
  int i = blockIdx.x * 256 + threadIdx.x;
  if (i < n4) {
    float4 v = ((const float4*)src)[i];
    ushort4 o;
    o.x = f2bf(v.x); o.y = f2bf(v.y); o.z = f2bf(v.z); o.w = f2bf(v.w);
    ((ushort4*)dst)[i] = o;
  }
}

// ============================================================================
// gemm_qk: C[4096,4096] = A[4096,2048] * B[4096,2048]^T -> bf16 QK buffer.
// BM=BN=256, BK=64, 8 waves (2M x 4N -> 128x64/wave), double-buffered LDS,
// 4 phases per K-tile (16 MFMA each), counted vmcnt.  256 blocks = 1 round.
// ============================================================================
__global__ __launch_bounds__(512, 2) void gemm_qk(
    const unsigned short* __restrict__ A, const unsigned short* __restrict__ B,
    unsigned short* __restrict__ QK) {
  extern __shared__ __align__(16) char smem[];
  const int tid = threadIdx.x;
  const int lane = tid & 63;
  const int wave = tid >> 6;
  const int quad = lane >> 4;
  const int l15 = lane & 15;
  const int bid = blockIdx.x;
  const int wgid = (bid & 7) * 32 + (bid >> 3);  // bijective XCD swizzle
  const int tm = wgid >> 4, tn = wgid & 15;
  const int m0 = tm * 256, n0 = tn * 256;
  const int wm = wave >> 2;  // 0..1
  const int wn = wave & 3;   // 0..3

  const unsigned short* Ag = A + (size_t)(m0 + wave * 8 + (lane >> 3)) * 2048 +
                             (((lane & 7) ^ (lane >> 3)) * 8);
  const unsigned short* Bg = B + (size_t)(n0 + wave * 8 + (lane >> 3)) * 2048 +
                             (((lane & 7) ^ (lane >> 3)) * 8);
  char* sd = smem + wave * 1024;

  const int arow0 = (wm * 128 + l15) * 128;  // byte base, A frag (mh=0,mi=0)
  const int brow0 = (wn * 64 + l15) * 128;
  const int sk0 = (quad ^ (l15 & 7)) * 16;
  const int sk1 = ((4 + quad) ^ (l15 & 7)) * 16;

  f32x4 acc[8][4] = {};
  bf16x8 a[4][2], bl[2][2], bh[2][2];

#define QSA(u, nb, ko) \
  gload_lds16(Ag + (size_t)(u) * 64 * 2048 + (ko), sd + (nb) * 65536 + (u) * 8192)
#define QSB(u, nb, ko) \
  gload_lds16(Bg + (size_t)(u) * 64 * 2048 + (ko), sd + (nb) * 65536 + 32768 + (u) * 8192)
#define QRA(mh, cb)                                                               \
  _Pragma("unroll") for (int mi = 0; mi < 4; mi++) {                              \
    a[mi][0] = *(const bf16x8*)(smem + (cb) * 65536 + arow0 + ((mh) * 64 + mi * 16) * 128 + sk0); \
    a[mi][1] = *(const bf16x8*)(smem + (cb) * 65536 + arow0 + ((mh) * 64 + mi * 16) * 128 + sk1); \
  }
#define QRB(dst, nh, cb)                                                          \
  _Pragma("unroll") for (int ni = 0; ni < 2; ni++) {                              \
    dst[ni][0] = *(const bf16x8*)(smem + (cb) * 65536 + 32768 + brow0 + ((nh) * 32 + ni * 16) * 128 + sk0); \
    dst[ni][1] = *(const bf16x8*)(smem + (cb) * 65536 + 32768 + brow0 + ((nh) * 32 + ni * 16) * 128 + sk1); \
  }
#define QMM(mh, bsrc, nh)                                                         \
  _Pragma("unroll") for (int mi = 0; mi < 4; mi++)                                \
  _Pragma("unroll") for (int ni = 0; ni < 2; ni++) {                              \
    acc[(mh) * 4 + mi][(nh) * 2 + ni] = __builtin_amdgcn_mfma_f32_16x16x32_bf16(  \
        a[mi][0], bsrc[ni][0], acc[(mh) * 4 + mi][(nh) * 2 + ni], 0, 0, 0);       \
    acc[(mh) * 4 + mi][(nh) * 2 + ni] = __builtin_amdgcn_mfma_f32_16x16x32_bf16(  \
        a[mi][1], bsrc[ni][1], acc[(mh) * 4 + mi][(nh) * 2 + ni], 0, 0, 0);       \
  }

  // prologue: tile 0 fully staged
  QSB(0, 0, 0); QSB(1, 0, 0); QSB(2, 0, 0); QSB(3, 0, 0);
  QSA(0, 0, 0); QSA(2, 0, 0); QSA(1, 0, 0); QSA(3, 0, 0);
  VMW(0);
  BARX();

#define QKTILE(t, cb, nb)                                                         \
  {                                                                               \
    const int ko = (((t) + 1) & 31) * 64;                                         \
    /* ph0 */                                                                     \
    QRA(0, cb); QRB(bl, 0, cb);                                                   \
    QSB(0, nb, ko); QSB(1, nb, ko);                                               \
    BARX(); LGK0(); PRIO(1); QMM(0, bl, 0); PRIO(0); BARX();                      \
    /* ph1 */                                                                     \
    QRB(bh, 1, cb);                                                               \
    QSB(2, nb, ko); QSB(3, nb, ko);                                               \
    BARX(); LGK0(); PRIO(1); QMM(0, bh, 1); PRIO(0); VMW(4); BARX();              \
    /* ph2 */                                                                     \
    QRA(1, cb);                                                                   \
    QSA(0, nb, ko); QSA(2, nb, ko);                                               \
    BARX(); LGK0(); PRIO(1); QMM(1, bl, 0); PRIO(0); BARX();                      \
    /* ph3 */                                                                     \
    QSA(1, nb, ko); QSA(3, nb, ko);                                               \
    PRIO(1); QMM(1, bh, 1); PRIO(0); VMW(2); BARX();                              \
  }

  for (int t = 0; t < 32; t += 2) {
    QKTILE(t, 0, 1);
    QKTILE(t + 1, 1, 0);
  }

  // epilogue: bf16 stores, row stride 4096
#pragma unroll
  for (int mi = 0; mi < 8; mi++)
#pragma unroll
    for (int ni = 0; ni < 4; ni++) {
      const int mm = m0 + wm * 128 + mi * 16 + quad * 4;
      const int nn = n0 + wn * 64 + ni * 16 + l15;
#pragma unroll
      for (int r = 0; r < 4; r++)
        QK[(size_t)(mm + r) * QSTRIDE + nn] = f2bf(acc[mi][ni][r]);
    }
#undef QSA
#undef QSB
#undef QRA
#undef QRB
#undef QMM
#undef QKTILE
}

// ============================================================================
// Shared 128x256 core for gemm_v / gemm_out: BM=128, BN=256, BK=64,
// 8 waves (4M x 2N -> 32x128/wave), TRIPLE-buffered LDS, 2 phases/K-tile,
// stage tile t+2 during t, single vmcnt(6)/tile.  256 blocks = 1 round.
// ============================================================================
#define VCORE_BODY(Aptr, Bptr)                                                    \
  const int tid = threadIdx.x;                                                    \
  const int lane = tid & 63;                                                      \
  const int wave = tid >> 6;                                                      \
  const int quad = lane >> 4;                                                     \
  const int l15 = lane & 15;                                                      \
  const int bid = blockIdx.x;                                                     \
  const int wgid = (bid & 7) * 32 + (bid >> 3);                                   \
  const int tm = wgid >> 3, tn = wgid & 7;                                        \
  const int m0 = tm * 128, n0 = tn * 256;                                         \
  const int wm = wave >> 1; /* 0..3 */                                            \
  const int wn = wave & 1;  /* 0..1 */                                            \
  const unsigned short* Ag = (Aptr) + (size_t)(m0 + wave * 8 + (lane >> 3)) * 2048 + \
                             (((lane & 7) ^ (lane >> 3)) * 8);                    \
  const unsigned short* Bg = (Bptr) + (size_t)(n0 + wave * 8 + (lane >> 3)) * 2048 + \
                             (((lane & 7) ^ (lane >> 3)) * 8);                    \
  char* sd = smem + wave * 1024;                                                  \
  const int arow0 = (wm * 32 + l15) * 128;                                        \
  const int brow0 = (wn * 128 + l15) * 128;                                       \
  const int sk0 = (quad ^ (l15 & 7)) * 16;                                        \
  const int sk1 = ((4 + quad) ^ (l15 & 7)) * 16;                                  \
  f32x4 acc[2][8] = {};                                                           \
  bf16x8 a[2][2], bl[4][2], bh[4][2];

#define VSA(u, nb, ko) \
  gload_lds16(Ag + (size_t)(u) * 64 * 2048 + (ko), sd + (nb) * 49152 + (u) * 8192)
#define VSB(u, nb, ko) \
  gload_lds16(Bg + (size_t)(u) * 64 * 2048 + (ko), sd + (nb) * 49152 + 16384 + (u) * 8192)
#define VRA(cb)                                                                   \
  _Pragma("unroll") for (int mi = 0; mi < 2; mi++) {                              \
    a[mi][0] = *(const bf16x8*)(smem + (cb) * 49152 + arow0 + mi * 2048 + sk0);   \
    a[mi][1] = *(const bf16x8*)(smem + (cb) * 49152 + arow0 + mi * 2048 + sk1);   \
  }
#define VRB(dst, nh, cb)                                                          \
  _Pragma("unroll") for (int ni = 0; ni < 4; ni++) {                              \
    dst[ni][0] = *(const bf16x8*)(smem + (cb) * 49152 + 16384 + brow0 + ((nh) * 64 + ni * 16) * 128 + sk0); \
    dst[ni][1] = *(const bf16x8*)(smem + (cb) * 49152 + 16384 + brow0 + ((nh) * 64 + ni * 16) * 128 + sk1); \
  }
#define VMM(bsrc, nh)                                                             \
  _Pragma("unroll") for (int mi = 0; mi < 2; mi++)                                \
  _Pragma("unroll") for (int ni = 0; ni < 4; ni++) {                              \
    acc[mi][(nh) * 4 + ni] = __builtin_amdgcn_mfma_f32_16x16x32_bf16(             \
        a[mi][0], bsrc[ni][0], acc[mi][(nh) * 4 + ni], 0, 0, 0);                  \
    acc[mi][(nh) * 4 + ni] = __builtin_amdgcn_mfma_f32_16x16x32_bf16(             \
        a[mi][1], bsrc[ni][1], acc[mi][(nh) * 4 + ni], 0, 0, 0);                  \
  }
#define VSTAGE6(nb, ko)                                                           \
  VSA(0, nb, ko); VSA(1, nb, ko); VSB(0, nb, ko);                                 \
  VSB(1, nb, ko); VSB(2, nb, ko); VSB(3, nb, ko);

#define VTILE(t, cb, nb)                                                          \
  {                                                                               \
    const int ko = (((t) + 2) & 31) * 64;                                         \
    /* ph0 */                                                                     \
    VRA(cb); VRB(bl, 0, cb);                                                      \
    VSA(0, nb, ko); VSA(1, nb, ko); VSB(0, nb, ko);                               \
    BARX(); LGK0(); PRIO(1); VMM(bl, 0); PRIO(0); BARX();                         \
    /* ph1 */                                                                     \
    VRB(bh, 1, cb);                                                               \
    VSB(1, nb, ko); VSB(2, nb, ko); VSB(3, nb, ko);                               \
    BARX(); LGK0(); PRIO(1); VMM(bh, 1); PRIO(0); VMW(6); BARX();                 \
  }

#define VCORE_LOOP()                                                              \
  VSTAGE6(0, 0);                                                                  \
  VSTAGE6(1, 64);                                                                 \
  VMW(6);                                                                         \
  BARX();                                                                         \
  for (int t = 0; t < 30; t += 3) {                                               \
    VTILE(t + 0, 0, 2);                                                           \
    VTILE(t + 1, 1, 0);                                                           \
    VTILE(t + 2, 2, 1);                                                           \
  }                                                                               \
  VTILE(30, 0, 2);                                                                \
  VTILE(31, 1, 0);

// ---------------- V-projection GEMM -> transposed bf16 Vt[bh][d][s] --------
__global__ __launch_bounds__(512, 2) void gemm_v(
    const unsigned short* __restrict__ A, const unsigned short* __restrict__ B,
    unsigned short* __restrict__ Vt) {
  extern __shared__ __align__(16) char smem[];
  VCORE_BODY(A, B);
  VCORE_LOOP();

  // transpose via LDS: T[2 heads][128 d][136 s-pad] bf16
  VMW(0);
  BARX();
  unsigned short* T = (unsigned short*)smem;
  const int h0 = n0 >> 7;  // = tn*2
  const int bb = m0 >> 11;
  const int sbase = m0 & (SEQ - 1);
#pragma unroll
  for (int mi = 0; mi < 2; mi++)
#pragma unroll
    for (int q = 0; q < 8; q++) {
      const int d = q * 16 + l15;
      const int slocal = wm * 32 + mi * 16 + quad * 4;
      ushort4 hv;
      hv.x = f2bf(acc[mi][q][0]);
      hv.y = f2bf(acc[mi][q][1]);
      hv.z = f2bf(acc[mi][q][2]);
      hv.w = f2bf(acc[mi][q][3]);
      *(ushort4*)(T + wn * 17408 + d * 136 + slocal) = hv;
    }
  BARX();
  const int hd2 = tid >> 8;          // 0..1
  const int d = (tid >> 1) & 127;
  const int sc = (tid & 1) * 64;
  const size_t vrow = ((size_t)((bb * NH + h0 + hd2) * HD + d)) * SEQ + sbase + sc;
#pragma unroll
  for (int j = 0; j < 8; j++) {
    float4 c4 = *(const float4*)(T + hd2 * 17408 + d * 136 + sc + j * 8);
    *(float4*)(Vt + vrow + j * 8) = c4;
  }
}

// ---------------- output-projection GEMM -> f32 C ---------------------------
__global__ __launch_bounds__(512, 2) void gemm_out(
    const unsigned short* __restrict__ A, const unsigned short* __restrict__ B,
    float* __restrict__ C) {
  extern __shared__ __align__(16) char smem[];
  VCORE_BODY(A, B);
  VCORE_LOOP();

#pragma unroll
  for (int mi = 0; mi < 2; mi++)
#pragma unroll
    for (int q = 0; q < 8; q++) {
      const int mm = m0 + wm * 32 + mi * 16 + quad * 4;
      const int nn = n0 + wn * 128 + q * 16 + l15;
#pragma unroll
      for (int r = 0; r < 4; r++)
        C[(size_t)(mm + r) * D_MODEL + nn] = acc[mi][q][r];
    }
}

// ---------------- flash attention v6 --------------------------------------
// v5 kept (full-rate bf16 K=32 PV, bpermute repack, rounded-p lsum) but V
// returns to double-buffered LDS staging (v5's direct-L2 V loads starved the
// matrix pipe: MfmaUtil 16%).  Vs layout [128 d][64 keys] bf16 with the
// GEMM-proven chunk^=row&7 swizzle: pre-swizzled global source, linear
// global_load_lds dest, un-swizzled ds_read_b128 (~2-way banks).
__global__ __launch_bounds__(256, 2) void flash_attn(
    const unsigned short* __restrict__ QK, const unsigned short* __restrict__ Vt,
    unsigned short* __restrict__ Og) {
  __shared__ __align__(16) unsigned short Ks[2][64 * 128];
  __shared__ __align__(16) unsigned short Vs[2][128 * 64];
  const int tid = threadIdx.x;
  const int lane = tid & 63;
  const int wave = tid >> 6;
  const int quad = lane >> 4;
  const int l15 = lane & 15;
  const int id = blockIdx.x;
  const int xr = id & 7;
  const int kk = id >> 3;
  const int bh = xr * 4 + (kk >> 4);
  const int b = bh >> 4, h = bh & 15;
  const int q0 = (kk & 15) * 128;

  const size_t kbase = (size_t)(b * SEQ) * QSTRIDE + D_MODEL + h * HD;
  const size_t vbase = (size_t)bh * HD * SEQ;

  bf16x8 qf[2][4];
#pragma unroll
  for (int t = 0; t < 2; t++)
#pragma unroll
    for (int kc = 0; kc < 4; kc++)
      qf[t][kc] = *(const bf16x8*)(QK + (size_t)(b * SEQ + q0 + wave * 32 + t * 16 + l15) * QSTRIDE +
                                   h * HD + kc * 32 + quad * 8);

  // K staging (swizzled source, linear LDS dest); rows 256B = 16 chunks
  const unsigned short* kg[4];
  int klofs[4];
#pragma unroll
  for (int i = 0; i < 4; i++) {
    int krow = wave * 16 + i * 4 + quad;
    int kc_ = l15 ^ (i * 4 + quad);
    kg[i] = QK + kbase + (size_t)krow * QSTRIDE + kc_ * 8;
    klofs[i] = (wave * 16 + i * 4) * 128;
  }

  // V staging: Vs rows = d (128B = 8 chunks of 8 keys); slot = chunk ^ (row&7)
  const unsigned short* vg[4];
  int vlofs[4];
#pragma unroll
  for (int u = 0; u < 4; u++) {
    int vrow = u * 32 + (tid >> 3);
    int vslot = tid & 7;
    int vchunk = vslot ^ (vrow & 7);
    vg[u] = Vt + vbase + (size_t)vrow * SEQ + vchunk * 8;
    vlofs[u] = vrow * 64 + vslot * 8;
  }

#pragma unroll
  for (int i = 0; i < 4; i++) gload_lds16(kg[i], &Ks[0][klofs[i]]);
#pragma unroll
  for (int u = 0; u < 4; u++) gload_lds16(vg[u], &Vs[0][vlofs[u]]);
#pragma unroll
  for (int i = 0; i < 4; i++) kg[i] += 64 * QSTRIDE;
#pragma unroll
  for (int u = 0; u < 4; u++) vg[u] += 64;
  VMW(0);
  __syncthreads();

  float lsum[2] = {0.f, 0.f};
  f32x4 Oa[2][8] = {};

  const int laA = l15 + 32 * (quad & 1);  // source lane for B-frag words 0,1
  const int laB = laA + 16;               // words 2,3
  const bool hi = quad >= 2;              // register select: js = 2g + (quad>>1)
  const int vsk0 = (quad ^ (l15 & 7)) * 8;        // V read slot, keys quad*8
  const int vsk1 = ((4 + quad) ^ (l15 & 7)) * 8;  // keys 32+quad*8

  for (int it = 0; it < SEQ / 64; ++it) {
    const int cur = it & 1;
    if (it < SEQ / 64 - 1) {
#pragma unroll
      for (int i = 0; i < 4; i++) gload_lds16(kg[i], &Ks[cur ^ 1][klofs[i]]);
#pragma unroll
      for (int u = 0; u < 4; u++) gload_lds16(vg[u], &Vs[cur ^ 1][vlofs[u]]);
#pragma unroll
      for (int i = 0; i < 4; i++) kg[i] += 64 * QSTRIDE;
#pragma unroll
      for (int u = 0; u < 4; u++) vg[u] += 64;
    }

    // ---- QK^T: 32 MFMA bf16 K=32 ----
    const unsigned short* kb = &Ks[cur][0];
    f32x4 sacc[2][4] = {};
    PRIO(1);
#pragma unroll
    for (int js = 0; js < 4; js++)
#pragma unroll
      for (int kc = 0; kc < 4; kc++) {
        bf16x8 kf = *(const bf16x8*)(kb + (js * 16 + l15) * 128 + (((kc * 4 + quad) ^ l15) * 8));
        sacc[0][js] = __builtin_amdgcn_mfma_f32_16x16x32_bf16(kf, qf[0][kc], sacc[0][js], 0, 0, 0);
        sacc[1][js] = __builtin_amdgcn_mfma_f32_16x16x32_bf16(kf, qf[1][kc], sacc[1][js], 0, 0, 0);
      }
    PRIO(0);

    // ---- softmax -> packed bf16 words pw[t][js][w]; lsum from ROUNDED p ----
    unsigned int pw[2][4][2];
#pragma unroll
    for (int t = 0; t < 2; t++)
#pragma unroll
      for (int js = 0; js < 4; js++) {
        float p0 = fast_exp2(sacc[t][js][0] * SCALE_LOG2E);
        float p1 = fast_exp2(sacc[t][js][1] * SCALE_LOG2E);
        float p2 = fast_exp2(sacc[t][js][2] * SCALE_LOG2E);
        float p3 = fast_exp2(sacc[t][js][3] * SCALE_LOG2E);
        unsigned int b0 = f2bf(p0), b1 = f2bf(p1), b2 = f2bf(p2), b3 = f2bf(p3);
        pw[t][js][0] = b0 | (b1 << 16);
        pw[t][js][1] = b2 | (b3 << 16);
        lsum[t] += (bf2f(b0) + bf2f(b1)) + (bf2f(b2) + bf2f(b3));
      }

    // ---- repack to K=32 B-frags: pb8[t][g] elem j = P[key=g*32+quad*8+j][q=l15]
    bf16x8 pb8[2][2];
#pragma unroll
    for (int t = 0; t < 2; t++)
#pragma unroll
      for (int g = 0; g < 2; g++) {
        const int j0 = 2 * g, j1 = 2 * g + 1;
        unsigned int a0 = bperm(laA, pw[t][j0][0]), c0 = bperm(laA, pw[t][j1][0]);
        unsigned int a1 = bperm(laA, pw[t][j0][1]), c1 = bperm(laA, pw[t][j1][1]);
        unsigned int a2 = bperm(laB, pw[t][j0][0]), c2 = bperm(laB, pw[t][j1][0]);
        unsigned int a3 = bperm(laB, pw[t][j0][1]), c3 = bperm(laB, pw[t][j1][1]);
        uint4 u;
        u.x = hi ? c0 : a0;
        u.y = hi ? c1 : a1;
        u.z = hi ? c2 : a2;
        u.w = hi ? c3 : a3;
        pb8[t][g] = __builtin_bit_cast(bf16x8, u);
      }

    // ---- PV: V frags from LDS (swizzled), bf16 K=32, full rate ----
    const unsigned short* vb = &Vs[cur][0];
    PRIO(1);
#pragma unroll
    for (int jt = 0; jt < 8; jt++) {
      const int vrow = (jt * 16 + l15) * 64;
      bf16x8 v0 = *(const bf16x8*)(vb + vrow + vsk0);
      bf16x8 v1 = *(const bf16x8*)(vb + vrow + vsk1);
      Oa[0][jt] = __builtin_amdgcn_mfma_f32_16x16x32_bf16(v0, pb8[0][0], Oa[0][jt], 0, 0, 0);
      Oa[1][jt] = __builtin_amdgcn_mfma_f32_16x16x32_bf16(v0, pb8[1][0], Oa[1][jt], 0, 0, 0);
      Oa[0][jt] = __builtin_amdgcn_mfma_f32_16x16x32_bf16(v1, pb8[0][1], Oa[0][jt], 0, 0, 0);
      Oa[1][jt] = __builtin_amdgcn_mfma_f32_16x16x32_bf16(v1, pb8[1][1], Oa[1][jt], 0, 0, 0);
    }
    PRIO(0);

    if (it < SEQ / 64 - 1) {
      VMW(0);  // own-wave staging for next buffer done
    }
    __syncthreads();
  }

  float inv[2];
#pragma unroll
  for (int t = 0; t < 2; t++) {
    float s = lsum[t];
    s += __shfl_xor(s, 16);
    s += __shfl_xor(s, 32);
    inv[t] = 1.0f / s;
  }

#pragma unroll
  for (int t = 0; t < 2; t++) {
    const size_t rowbase = (size_t)(b * SEQ + q0 + wave * 32 + t * 16 + l15) * D_MODEL + h * HD;
#pragma unroll
    for (int jt = 0; jt < 8; jt++) {
      ushort4 o;
      o.x = f2bf(Oa[t][jt][0] * inv[t]);
      o.y = f2bf(Oa[t][jt][1] * inv[t]);
      o.z = f2bf(Oa[t][jt][2] * inv[t]);
      o.w = f2bf(Oa[t][jt][3] * inv[t]);
      *(ushort4*)(Og + rowbase + jt * 16 + quad * 4) = o;
    }
  }
}

// ---------------- launcher ----------------
extern "C" void kernel_launch(void* const* d_in, const int* in_sizes, int n_in,
                              void* d_out, int out_size, void* d_ws, size_t ws_size,
                              hipStream_t stream) {
  const float* x = (const float*)d_in[0];
  const float* wq = (const float*)d_in[1];
  const float* wk = (const float*)d_in[2];
  const float* wv = (const float*)d_in[3];
  const float* wo = (const float*)d_in[4];
  float* out = (float*)d_out;
  char* ws = (char*)d_ws;
  const size_t MB = 1u << 20;
  if (ws_size < 96 * MB) return;

  unsigned short* xb = (unsigned short*)(ws);             // 16 MB (reused as Ab)
  unsigned short* wqkv = (unsigned short*)(ws + 16 * MB); // 24 MB [6144,2048]
  unsigned short* wob = (unsigned short*)(ws + 40 * MB);  // 8 MB
  unsigned short* QKb = (unsigned short*)(ws + 48 * MB);  // 32 MB [4096,4096]
  unsigned short* Vtb = (unsigned short*)(ws + 80 * MB);  // 16 MB bf16
  unsigned short* Ab = xb;

  static int lds_set = 0;
  if (!lds_set) {
    hipFuncSetAttribute((const void*)gemm_qk,
                        hipFuncAttributeMaxDynamicSharedMemorySize, 131072);
    hipFuncSetAttribute((const void*)gemm_v,
                        hipFuncAttributeMaxDynamicSharedMemorySize, 147456);
    hipFuncSetAttribute((const void*)gemm_out,
                        hipFuncAttributeMaxDynamicSharedMemorySize, 147456);
    lds_set = 1;
  }

  cvt_all<<<dim3(8192, 5), 256, 0, stream>>>(x, wq, wk, wv, wo, xb, wqkv, wob);

  gemm_qk<<<256, 512, 131072, stream>>>(xb, wqkv, QKb);
  gemm_v<<<256, 512, 147456, stream>>>(xb, wqkv + (size_t)4096 * 2048, Vtb);

  flash_attn<<<512, 256, 0, stream>>>(QKb, Vtb, Ab);

  gemm_out<<<256, 512, 147456, stream>>>(Ab, wob, out);
}

// Round 8
// 363.051 us; speedup vs baseline: 1.1670x; 1.0005x over previous
//
#include <hip/hip_runtime.h>

#define D_MODEL 2048
#define SEQ 2048
#define BATCH 2
#define NH 16
#define HD 128
#define MTOT 4096   // BATCH*SEQ
#define NQKV 6144   // 3*D_MODEL
#define QSTRIDE 4096  // QK buffer row stride (Q cols 0..2047, K cols 2048..4095)

// 1/sqrt(128) * log2(e)
static constexpr float SCALE_LOG2E = 0.08838834764831845f * 1.4426950408889634f;

typedef __bf16 bf16x8 __attribute__((ext_vector_type(8)));
typedef float f32x4 __attribute__((ext_vector_type(4)));

__device__ inline unsigned short f2bf(float f) {
  unsigned int u = __builtin_bit_cast(unsigned int, f);
  u += 0x7fffu + ((u >> 16) & 1u);
  return (unsigned short)(u >> 16);
}

__device__ inline float fast_exp2(float x) {
#if __has_builtin(__builtin_amdgcn_exp2f)
  return __builtin_amdgcn_exp2f(x);
#else
  return exp2f(x);
#endif
}

__device__ inline unsigned int bperm(int srcLane, unsigned int v) {
  return (unsigned int)__builtin_amdgcn_ds_bpermute(srcLane << 2, (int)v);
}

__device__ inline void gload_lds16(const void* g, void* s) {
  __builtin_amdgcn_global_load_lds(
      (__attribute__((address_space(1))) void*)g,
      (__attribute__((address_space(3))) void*)s, 16, 0, 0);
}

#define BARX() __builtin_amdgcn_s_barrier()
#define PRIO(x) __builtin_amdgcn_s_setprio(x)
#define LGK0()                                              \
  do {                                                      \
    asm volatile("s_waitcnt lgkmcnt(0)" ::: "memory");      \
    __builtin_amdgcn_sched_barrier(0);                      \
  } while (0)
#define VMW(n) asm volatile("s_waitcnt vmcnt(" #n ")" ::: "memory")

// ---------------- fused fp32 -> bf16 conversion (all 5 inputs) -------------
__global__ __launch_bounds__(256) void cvt_all(
    const float* __restrict__ x, const float* __restrict__ wq,
    const float* __restrict__ wk, const float* __restrict__ wv,
    const float* __restrict__ wo, unsigned short* __restrict__ xb,
    unsigned short* __restrict__ wqkv, unsigned short* __restrict__ wob) {
  const int y = blockIdx.y;
  const float* src;
  unsigned short* dst;
  int n4;
  if (y == 0) { src = x; dst = xb; n4 = MTOT * D_MODEL / 4; }
  else if (y == 4) { src = wo; dst = wob; n4 = D_MODEL * D_MODEL / 4; }
  else {
    src = (y == 1) ? wq : (y == 2) ? wk : wv;
    dst = wqkv + (size_t)(y - 1) * D_MODEL * D_MODEL;
    n4 = D_MODEL * D_MODEL / 4;
  }
  int i = blockIdx.x * 256 + threadIdx.x;
  if (i < n4) {
    float4 v = ((const float4*)src)[i];
    ushort4 o;
    o.x = f2bf(v.x); o.y = f2bf(v.y); o.z = f2bf(v.z); o.w = f2bf(v.w);
    ((ushort4*)dst)[i] = o;
  }
}

// ============================================================================
// gemm_qk: C[4096,4096] = A[4096,2048] * B[4096,2048]^T -> bf16 QK buffer.
// Q columns (n<2048) are pre-scaled by SCALE_LOG2E so flash_attn's softmax
// needs no per-element multiply.  BM=BN=256, BK=64, 8 waves, double-buffered
// LDS, 4 phases per K-tile, counted vmcnt.  256 blocks = 1 round.
// ============================================================================
__global__ __launch_bounds__(512, 2) void gemm_qk(
    const unsigned short* __restrict__ A, const unsigned short* __restrict__ B,
    unsigned short* __restrict__ QK) {
  extern __shared__ __align__(16) char smem[];
  const int tid = threadIdx.x;
  const int lane = tid & 63;
  const int wave = tid >> 6;
  const int quad = lane >> 4;
  const int l15 = lane & 15;
  const int bid = blockIdx.x;
  const int wgid = (bid & 7) * 32 + (bid >> 3);  // bijective XCD swizzle
  const int tm = wgid >> 4, tn = wgid & 15;
  const int m0 = tm * 256, n0 = tn * 256;
  const int wm = wave >> 2;  // 0..1
  const int wn = wave & 3;   // 0..3

  const unsigned short* Ag = A + (size_t)(m0 + wave * 8 + (lane >> 3)) * 2048 +
                             (((lane & 7) ^ (lane >> 3)) * 8);
  const unsigned short* Bg = B + (size_t)(n0 + wave * 8 + (lane >> 3)) * 2048 +
                             (((lane & 7) ^ (lane >> 3)) * 8);
  char* sd = smem + wave * 1024;

  const int arow0 = (wm * 128 + l15) * 128;  // byte base, A frag (mh=0,mi=0)
  const int brow0 = (wn * 64 + l15) * 128;
  const int sk0 = (quad ^ (l15 & 7)) * 16;
  const int sk1 = ((4 + quad) ^ (l15 & 7)) * 16;

  f32x4 acc[8][4] = {};
  bf16x8 a[4][2], bl[2][2], bh[2][2];

#define QSA(u, nb, ko) \
  gload_lds16(Ag + (size_t)(u) * 64 * 2048 + (ko), sd + (nb) * 65536 + (u) * 8192)
#define QSB(u, nb, ko) \
  gload_lds16(Bg + (size_t)(u) * 64 * 2048 + (ko), sd + (nb) * 65536 + 32768 + (u) * 8192)
#define QRA(mh, cb)                                                               \
  _Pragma("unroll") for (int mi = 0; mi < 4; mi++) {                              \
    a[mi][0] = *(const bf16x8*)(smem + (cb) * 65536 + arow0 + ((mh) * 64 + mi * 16) * 128 + sk0); \
    a[mi][1] = *(const bf16x8*)(smem + (cb) * 65536 + arow0 + ((mh) * 64 + mi * 16) * 128 + sk1); \
  }
#define QRB(dst, nh, cb)                                                          \
  _Pragma("unroll") for (int ni = 0; ni < 2; ni++) {                              \
    dst[ni][0] = *(const bf16x8*)(smem + (cb) * 65536 + 32768 + brow0 + ((nh) * 32 + ni * 16) * 128 + sk0); \
    dst[ni][1] = *(const bf16x8*)(smem + (cb) * 65536 + 32768 + brow0 + ((nh) * 32 + ni * 16) * 128 + sk1); \
  }
#define QMM(mh, bsrc, nh)                                                         \
  _Pragma("unroll") for (int mi = 0; mi < 4; mi++)                                \
  _Pragma("unroll") for (int ni = 0; ni < 2; ni++) {                              \
    acc[(mh) * 4 + mi][(nh) * 2 + ni] = __builtin_amdgcn_mfma_f32_16x16x32_bf16(  \
        a[mi][0], bsrc[ni][0], acc[(mh) * 4 + mi][(nh) * 2 + ni], 0, 0, 0);       \
    acc[(mh) * 4 + mi][(nh) * 2 + ni] = __builtin_amdgcn_mfma_f32_16x16x32_bf16(  \
        a[mi][1], bsrc[ni][1], acc[(mh) * 4 + mi][(nh) * 2 + ni], 0, 0, 0);       \
  }

  // prologue: tile 0 fully staged
  QSB(0, 0, 0); QSB(1, 0, 0); QSB(2, 0, 0); QSB(3, 0, 0);
  QSA(0, 0, 0); QSA(2, 0, 0); QSA(1, 0, 0); QSA(3, 0, 0);
  VMW(0);
  BARX();

#define QKTILE(t, cb, nb)                                                         \
  {                                                                               \
    const int ko = (((t) + 1) & 31) * 64;                                         \
    /* ph0 */                                                                     \
    QRA(0, cb); QRB(bl, 0, cb);                                                   \
    QSB(0, nb, ko); QSB(1, nb, ko);                                               \
    BARX(); LGK0(); PRIO(1); QMM(0, bl, 0); PRIO(0); BARX();                      \
    /* ph1 */                                                                     \
    QRB(bh, 1, cb);                                                               \
    QSB(2, nb, ko); QSB(3, nb, ko);                                               \
    BARX(); LGK0(); PRIO(1); QMM(0, bh, 1); PRIO(0); VMW(4); BARX();              \
    /* ph2 */                                                                     \
    QRA(1, cb);                                                                   \
    QSA(0, nb, ko); QSA(2, nb, ko);                                               \
    BARX(); LGK0(); PRIO(1); QMM(1, bl, 0); PRIO(0); BARX();                      \
    /* ph3 */                                                                     \
    QSA(1, nb, ko); QSA(3, nb, ko);                                               \
    PRIO(1); QMM(1, bh, 1); PRIO(0); VMW(2); BARX();                              \
  }

  for (int t = 0; t < 32; t += 2) {
    QKTILE(t, 0, 1);
    QKTILE(t + 1, 1, 0);
  }

  // epilogue: bf16 stores, row stride 4096; Q columns pre-scaled
  const float qs = (n0 < 2048) ? SCALE_LOG2E : 1.0f;
#pragma unroll
  for (int mi = 0; mi < 8; mi++)
#pragma unroll
    for (int ni = 0; ni < 4; ni++) {
      const int mm = m0 + wm * 128 + mi * 16 + quad * 4;
      const int nn = n0 + wn * 64 + ni * 16 + l15;
#pragma unroll
      for (int r = 0; r < 4; r++)
        QK[(size_t)(mm + r) * QSTRIDE + nn] = f2bf(acc[mi][ni][r] * qs);
    }
#undef QSA
#undef QSB
#undef QRA
#undef QRB
#undef QMM
#undef QKTILE
}

// ============================================================================
// Shared 128x256 core for gemm_v / gemm_out: BM=128, BN=256, BK=64,
// 8 waves (4M x 2N -> 32x128/wave), TRIPLE-buffered LDS, 2 phases/K-tile,
// stage tile t+2 during t, single vmcnt(6)/tile.  256 blocks = 1 round.
// ============================================================================
#define VCORE_BODY(Aptr, Bptr)                                                    \
  const int tid = threadIdx.x;                                                    \
  const int lane = tid & 63;                                                      \
  const int wave = tid >> 6;                                                      \
  const int quad = lane >> 4;                                                     \
  const int l15 = lane & 15;                                                      \
  const int bid = blockIdx.x;                                                     \
  const int wgid = (bid & 7) * 32 + (bid >> 3);                                   \
  const int tm = wgid >> 3, tn = wgid & 7;                                        \
  const int m0 = tm * 128, n0 = tn * 256;                                         \
  const int wm = wave >> 1; /* 0..3 */                                            \
  const int wn = wave & 1;  /* 0..1 */                                            \
  const unsigned short* Ag = (Aptr) + (size_t)(m0 + wave * 8 + (lane >> 3)) * 2048 + \
                             (((lane & 7) ^ (lane >> 3)) * 8);                    \
  const unsigned short* Bg = (Bptr) + (size_t)(n0 + wave * 8 + (lane >> 3)) * 2048 + \
                             (((lane & 7) ^ (lane >> 3)) * 8);                    \
  char* sd = smem + wave * 1024;                                                  \
  const int arow0 = (wm * 32 + l15) * 128;                                        \
  const int brow0 = (wn * 128 + l15) * 128;                                       \
  const int sk0 = (quad ^ (l15 & 7)) * 16;                                        \
  const int sk1 = ((4 + quad) ^ (l15 & 7)) * 16;                                  \
  f32x4 acc[2][8] = {};                                                           \
  bf16x8 a[2][2], bl[4][2], bh[4][2];

#define VSA(u, nb, ko) \
  gload_lds16(Ag + (size_t)(u) * 64 * 2048 + (ko), sd + (nb) * 49152 + (u) * 8192)
#define VSB(u, nb, ko) \
  gload_lds16(Bg + (size_t)(u) * 64 * 2048 + (ko), sd + (nb) * 49152 + 16384 + (u) * 8192)
#define VRA(cb)                                                                   \
  _Pragma("unroll") for (int mi = 0; mi < 2; mi++) {                              \
    a[mi][0] = *(const bf16x8*)(smem + (cb) * 49152 + arow0 + mi * 2048 + sk0);   \
    a[mi][1] = *(const bf16x8*)(smem + (cb) * 49152 + arow0 + mi * 2048 + sk1);   \
  }
#define VRB(dst, nh, cb)                                                          \
  _Pragma("unroll") for (int ni = 0; ni < 4; ni++) {                              \
    dst[ni][0] = *(const bf16x8*)(smem + (cb) * 49152 + 16384 + brow0 + ((nh) * 64 + ni * 16) * 128 + sk0); \
    dst[ni][1] = *(const bf16x8*)(smem + (cb) * 49152 + 16384 + brow0 + ((nh) * 64 + ni * 16) * 128 + sk1); \
  }
#define VMM(bsrc, nh)                                                             \
  _Pragma("unroll") for (int mi = 0; mi < 2; mi++)                                \
  _Pragma("unroll") for (int ni = 0; ni < 4; ni++) {                              \
    acc[mi][(nh) * 4 + ni] = __builtin_amdgcn_mfma_f32_16x16x32_bf16(             \
        a[mi][0], bsrc[ni][0], acc[mi][(nh) * 4 + ni], 0, 0, 0);                  \
    acc[mi][(nh) * 4 + ni] = __builtin_amdgcn_mfma_f32_16x16x32_bf16(             \
        a[mi][1], bsrc[ni][1], acc[mi][(nh) * 4 + ni], 0, 0, 0);                  \
  }
#define VSTAGE6(nb, ko)                                                           \
  VSA(0, nb, ko); VSA(1, nb, ko); VSB(0, nb, ko);                                 \
  VSB(1, nb, ko); VSB(2, nb, ko); VSB(3, nb, ko);

#define VTILE(t, cb, nb)                                                          \
  {                                                                               \
    const int ko = (((t) + 2) & 31) * 64;                                         \
    /* ph0 */                                                                     \
    VRA(cb); VRB(bl, 0, cb);                                                      \
    VSA(0, nb, ko); VSA(1, nb, ko); VSB(0, nb, ko);                               \
    BARX(); LGK0(); PRIO(1); VMM(bl, 0); PRIO(0); BARX();                         \
    /* ph1 */                                                                     \
    VRB(bh, 1, cb);                                                               \
    VSB(1, nb, ko); VSB(2, nb, ko); VSB(3, nb, ko);                               \
    BARX(); LGK0(); PRIO(1); VMM(bh, 1); PRIO(0); VMW(6); BARX();                 \
  }

#define VCORE_LOOP()                                                              \
  VSTAGE6(0, 0);                                                                  \
  VSTAGE6(1, 64);                                                                 \
  VMW(6);                                                                         \
  BARX();                                                                         \
  for (int t = 0; t < 30; t += 3) {                                               \
    VTILE(t + 0, 0, 2);                                                           \
    VTILE(t + 1, 1, 0);                                                           \
    VTILE(t + 2, 2, 1);                                                           \
  }                                                                               \
  VTILE(30, 0, 2);                                                                \
  VTILE(31, 1, 0);

// ---------------- V-projection GEMM -> transposed bf16 Vt[bh][d][s] --------
__global__ __launch_bounds__(512, 2) void gemm_v(
    const unsigned short* __restrict__ A, const unsigned short* __restrict__ B,
    unsigned short* __restrict__ Vt) {
  extern __shared__ __align__(16) char smem[];
  VCORE_BODY(A, B);
  VCORE_LOOP();

  // transpose via LDS: T[2 heads][128 d][136 s-pad] bf16
  VMW(0);
  BARX();
  unsigned short* T = (unsigned short*)smem;
  const int h0 = n0 >> 7;  // = tn*2
  const int bb = m0 >> 11;
  const int sbase = m0 & (SEQ - 1);
#pragma unroll
  for (int mi = 0; mi < 2; mi++)
#pragma unroll
    for (int q = 0; q < 8; q++) {
      const int d = q * 16 + l15;
      const int slocal = wm * 32 + mi * 16 + quad * 4;
      ushort4 hv;
      hv.x = f2bf(acc[mi][q][0]);
      hv.y = f2bf(acc[mi][q][1]);
      hv.z = f2bf(acc[mi][q][2]);
      hv.w = f2bf(acc[mi][q][3]);
      *(ushort4*)(T + wn * 17408 + d * 136 + slocal) = hv;
    }
  BARX();
  const int hd2 = tid >> 8;          // 0..1
  const int d = (tid >> 1) & 127;
  const int sc = (tid & 1) * 64;
  const size_t vrow = ((size_t)((bb * NH + h0 + hd2) * HD + d)) * SEQ + sbase + sc;
#pragma unroll
  for (int j = 0; j < 8; j++) {
    float4 c4 = *(const float4*)(T + hd2 * 17408 + d * 136 + sc + j * 8);
    *(float4*)(Vt + vrow + j * 8) = c4;
  }
}

// ---------------- output-projection GEMM -> f32 C ---------------------------
__global__ __launch_bounds__(512, 2) void gemm_out(
    const unsigned short* __restrict__ A, const unsigned short* __restrict__ B,
    float* __restrict__ C) {
  extern __shared__ __align__(16) char smem[];
  VCORE_BODY(A, B);
  VCORE_LOOP();

#pragma unroll
  for (int mi = 0; mi < 2; mi++)
#pragma unroll
    for (int q = 0; q < 8; q++) {
      const int mm = m0 + wm * 32 + mi * 16 + quad * 4;
      const int nn = n0 + wn * 128 + q * 16 + l15;
#pragma unroll
      for (int r = 0; r < 4; r++)
        C[(size_t)(mm + r) * D_MODEL + nn] = acc[mi][q][r];
    }
}

// ---------------- flash attention v7 --------------------------------------
// v6 numerics kept (full-rate bf16 K=32 PV, bpermute repack, rounded-p lsum)
// but restructured for TLP: 512-thread blocks (8 waves x 16 Q-rows), same
// 64KB LDS, 2 blocks/CU -> 16 waves/CU (v6: 7).  Per-wave serial chain
// halves; 4 waves/SIMD hide bperm/MFMA latency.  VALU diet: Q pre-scaled in
// gemm_qk (no per-element mul) and native __bf16 casts (compiler cvt_pk).
__global__ __launch_bounds__(512, 4) void flash_attn(
    const unsigned short* __restrict__ QK, const unsigned short* __restrict__ Vt,
    unsigned short* __restrict__ Og) {
  __shared__ __align__(16) unsigned short Ks[2][64 * 128];
  __shared__ __align__(16) unsigned short Vs[2][128 * 64];
  const int tid = threadIdx.x;
  const int lane = tid & 63;
  const int wave = tid >> 6;  // 0..7
  const int quad = lane >> 4;
  const int l15 = lane & 15;
  const int id = blockIdx.x;
  const int xr = id & 7;
  const int kk = id >> 3;
  const int bh = xr * 4 + (kk >> 4);
  const int b = bh >> 4, h = bh & 15;
  const int q0 = (kk & 15) * 128;

  const size_t kbase = (size_t)(b * SEQ) * QSTRIDE + D_MODEL + h * HD;
  const size_t vbase = (size_t)bh * HD * SEQ;

  // Q fragments: wave owns rows q0 + wave*16 + l15 (Q pre-scaled by gemm_qk)
  bf16x8 qf[4];
#pragma unroll
  for (int kc = 0; kc < 4; kc++)
    qf[kc] = *(const bf16x8*)(QK + (size_t)(b * SEQ + q0 + wave * 16 + l15) * QSTRIDE +
                              h * HD + kc * 32 + quad * 8);

  // K staging: 2 loads/thread; Ks rows 256B = 16 slots, slot = chunk^(row&15)
  const unsigned short* kg[2];
  int klofs[2];
#pragma unroll
  for (int u = 0; u < 2; u++) {
    const int krow = u * 32 + (tid >> 4);
    const int chunk = (tid & 15) ^ (krow & 15);
    kg[u] = QK + kbase + (size_t)krow * QSTRIDE + chunk * 8;
    klofs[u] = u * 4096 + tid * 8;
  }
  // V staging: 2 loads/thread; Vs rows 128B = 8 slots, slot = chunk^(row&7)
  const unsigned short* vg[2];
  int vlofs[2];
#pragma unroll
  for (int u = 0; u < 2; u++) {
    const int vrow = u * 64 + (tid >> 3);
    const int chunk = (tid & 7) ^ (vrow & 7);
    vg[u] = Vt + vbase + (size_t)vrow * SEQ + chunk * 8;
    vlofs[u] = u * 4096 + tid * 8;
  }

#pragma unroll
  for (int u = 0; u < 2; u++) gload_lds16(kg[u], &Ks[0][klofs[u]]);
#pragma unroll
  for (int u = 0; u < 2; u++) gload_lds16(vg[u], &Vs[0][vlofs[u]]);
#pragma unroll
  for (int u = 0; u < 2; u++) { kg[u] += 64 * QSTRIDE; vg[u] += 64; }
  VMW(0);
  __syncthreads();

  float lsum = 0.f;
  f32x4 Oa[8] = {};

  const int laA = l15 + 32 * (quad & 1);  // source lane for B-frag words 0,1
  const int laB = laA + 16;               // words 2,3
  const bool hi = quad >= 2;              // register select: j = 2g + (quad>>1)
  const int vsk0 = (quad ^ (l15 & 7)) * 8;        // V read slot, keys quad*8
  const int vsk1 = ((4 + quad) ^ (l15 & 7)) * 8;  // keys 32+quad*8

  for (int it = 0; it < SEQ / 64; ++it) {
    const int cur = it & 1;
    if (it < SEQ / 64 - 1) {
#pragma unroll
      for (int u = 0; u < 2; u++) gload_lds16(kg[u], &Ks[cur ^ 1][klofs[u]]);
#pragma unroll
      for (int u = 0; u < 2; u++) gload_lds16(vg[u], &Vs[cur ^ 1][vlofs[u]]);
#pragma unroll
      for (int u = 0; u < 2; u++) { kg[u] += 64 * QSTRIDE; vg[u] += 64; }
    }

    // ---- QK^T: 16 MFMA bf16 K=32 (S pre-scaled via Q) ----
    const unsigned short* kb = &Ks[cur][0];
    f32x4 sacc[4] = {};
    PRIO(1);
#pragma unroll
    for (int js = 0; js < 4; js++)
#pragma unroll
      for (int kc = 0; kc < 4; kc++) {
        bf16x8 kf = *(const bf16x8*)(kb + (js * 16 + l15) * 128 + (((kc * 4 + quad) ^ l15) * 8));
        sacc[js] = __builtin_amdgcn_mfma_f32_16x16x32_bf16(kf, qf[kc], sacc[js], 0, 0, 0);
      }
    PRIO(0);

    // ---- softmax: p = 2^S, round to bf16 (native cast -> cvt_pk), pack;
    //      lsum accumulates the ROUNDED values (num/denom consistent) ----
    unsigned int pw[4][2];
#pragma unroll
    for (int js = 0; js < 4; js++) {
      __bf16 b0 = (__bf16)fast_exp2(sacc[js][0]);
      __bf16 b1 = (__bf16)fast_exp2(sacc[js][1]);
      __bf16 b2 = (__bf16)fast_exp2(sacc[js][2]);
      __bf16 b3 = (__bf16)fast_exp2(sacc[js][3]);
      lsum += ((float)b0 + (float)b1) + ((float)b2 + (float)b3);
      pw[js][0] = (unsigned int)__builtin_bit_cast(unsigned short, b0) |
                  ((unsigned int)__builtin_bit_cast(unsigned short, b1) << 16);
      pw[js][1] = (unsigned int)__builtin_bit_cast(unsigned short, b2) |
                  ((unsigned int)__builtin_bit_cast(unsigned short, b3) << 16);
    }

    // ---- repack to K=32 B-frags: pb8[g] elem j = P[key=g*32+quad*8+j][q=l15]
    bf16x8 pb8[2];
#pragma unroll
    for (int g = 0; g < 2; g++) {
      const int j0 = 2 * g, j1 = 2 * g + 1;
      unsigned int a0 = bperm(laA, pw[j0][0]), c0 = bperm(laA, pw[j1][0]);
      unsigned int a1 = bperm(laA, pw[j0][1]), c1 = bperm(laA, pw[j1][1]);
      unsigned int a2 = bperm(laB, pw[j0][0]), c2 = bperm(laB, pw[j1][0]);
      unsigned int a3 = bperm(laB, pw[j0][1]), c3 = bperm(laB, pw[j1][1]);
      uint4 u;
      u.x = hi ? c0 : a0;
      u.y = hi ? c1 : a1;
      u.z = hi ? c2 : a2;
      u.w = hi ? c3 : a3;
      pb8[g] = __builtin_bit_cast(bf16x8, u);
    }

    // ---- PV: V frags from LDS (swizzled), bf16 K=32, full rate ----
    const unsigned short* vb = &Vs[cur][0];
    PRIO(1);
#pragma unroll
    for (int jt = 0; jt < 8; jt++) {
      const int vrow = (jt * 16 + l15) * 64;
      bf16x8 v0 = *(const bf16x8*)(vb + vrow + vsk0);
      bf16x8 v1 = *(const bf16x8*)(vb + vrow + vsk1);
      Oa[jt] = __builtin_amdgcn_mfma_f32_16x16x32_bf16(v0, pb8[0], Oa[jt], 0, 0, 0);
      Oa[jt] = __builtin_amdgcn_mfma_f32_16x16x32_bf16(v1, pb8[1], Oa[jt], 0, 0, 0);
    }
    PRIO(0);

    if (it < SEQ / 64 - 1) {
      VMW(0);  // own-wave staging for next buffer proven before barrier
    }
    __syncthreads();
  }

  // reduce lsum over the 4 quads holding this q-column's keys
  float s = lsum;
  s += __shfl_xor(s, 16);
  s += __shfl_xor(s, 32);
  const float inv = 1.0f / s;

  const size_t rowbase = (size_t)(b * SEQ + q0 + wave * 16 + l15) * D_MODEL + h * HD;
#pragma unroll
  for (int jt = 0; jt < 8; jt++) {
    ushort4 o;
    o.x = f2bf(Oa[jt][0] * inv);
    o.y = f2bf(Oa[jt][1] * inv);
    o.z = f2bf(Oa[jt][2] * inv);
    o.w = f2bf(Oa[jt][3] * inv);
    *(ushort4*)(Og + rowbase + jt * 16 + quad * 4) = o;
  }
}

// ---------------- launcher ----------------
extern "C" void kernel_launch(void* const* d_in, const int* in_sizes, int n_in,
                              void* d_out, int out_size, void* d_ws, size_t ws_size,
                              hipStream_t stream) {
  const float* x = (const float*)d_in[0];
  const float* wq = (const float*)d_in[1];
  const float* wk = (const float*)d_in[2];
  const float* wv = (const float*)d_in[3];
  const float* wo = (const float*)d_in[4];
  float* out = (float*)d_out;
  char* ws = (char*)d_ws;
  const size_t MB = 1u << 20;
  if (ws_size < 96 * MB) return;

  unsigned short* xb = (unsigned short*)(ws);             // 16 MB (reused as Ab)
  unsigned short* wqkv = (unsigned short*)(ws + 16 * MB); // 24 MB [6144,2048]
  unsigned short* wob = (unsigned short*)(ws + 40 * MB);  // 8 MB
  unsigned short* QKb = (unsigned short*)(ws + 48 * MB);  // 32 MB [4096,4096]
  unsigned short* Vtb = (unsigned short*)(ws + 80 * MB);  // 16 MB bf16
  unsigned short* Ab = xb;

  static int lds_set = 0;
  if (!lds_set) {
    hipFuncSetAttribute((const void*)gemm_qk,
                        hipFuncAttributeMaxDynamicSharedMemorySize, 131072);
    hipFuncSetAttribute((const void*)gemm_v,
                        hipFuncAttributeMaxDynamicSharedMemorySize, 147456);
    hipFuncSetAttribute((const void*)gemm_out,
                        hipFuncAttributeMaxDynamicSharedMemorySize, 147456);
    lds_set = 1;
  }

  cvt_all<<<dim3(8192, 5), 256, 0, stream>>>(x, wq, wk, wv, wo, xb, wqkv, wob);

  gemm_qk<<<256, 512, 131072, stream>>>(xb, wqkv, QKb);
  gemm_v<<<256, 512, 147456, stream>>>(xb, wqkv + (size_t)4096 * 2048, Vtb);

  flash_attn<<<512, 512, 0, stream>>>(QKb, Vtb, Ab);

  gemm_out<<<256, 512, 147456, stream>>>(Ab, wob, out);
}